// Round 3
// baseline (802.413 us; speedup 1.0000x reference)
//
#include <hip/hip_runtime.h>
#include <hip/hip_bf16.h>

#define B_ 2
#define S_ 2048
#define H_ 16
#define D_ 128
#define HD_ (H_ * D_)
#define KVB 64
#define NTILE (S_ / KVB)
#define BQ 128

typedef short bf16x8 __attribute__((ext_vector_type(8)));
typedef float f32x16 __attribute__((ext_vector_type(16)));

union BF8u { unsigned u[4]; bf16x8 v; };
union F4u { float4 v; float x4[4]; };

__device__ __forceinline__ unsigned pk2(float lo, float hi) {
    __hip_bfloat162 h = __float22bfloat162_rn(make_float2(lo, hi));
    union { __hip_bfloat162 h; unsigned u; } c; c.h = h;
    return c.u;
}

__global__ __launch_bounds__(256, 4)
void attn_fwd_kernel(const float* __restrict__ qg,
                     const float* __restrict__ kg,
                     const float* __restrict__ vg,
                     float* __restrict__ outg,
                     float* __restrict__ lseg)
{
    // Single-buffered (32 KiB): in-flight tile lives in registers (T14 split),
    // so the second LDS buffer bought nothing but halved occupancy.
    __shared__ unsigned short Kb[KVB * D_];   // [kv][d] bf16, swizzled
    __shared__ unsigned short Vb[D_ * KVB];   // [d][kv] bf16 (V^T), swizzled

    const int tid = threadIdx.x;
    const int lane = tid & 63;
    const int wv = tid >> 6;
    const int rl = lane & 31;
    const int h2 = lane >> 5;

    // XCD-aware swizzle (512 = 8*64, bijective)
    const int bid = blockIdx.x;
    const int L = (bid & 7) * 64 + (bid >> 3);
    const int bh = L >> 4;
    const int qt = L & 15;
    const int b = bh >> 4, h = bh & 15;
    const int q0 = qt * BQ;

    const size_t base = (size_t)b * S_ * HD_ + (size_t)h * D_;

    // ---- staging thread maps (phase-conflict-free)
    const int krow = tid >> 2;                    // 0..63
    const int kc = tid & 3;
    const int va = (tid & 3) | ((tid >> 7) << 2); // 0..7 kv-slot
    const int vbc = (tid >> 2) & 31;              // 0..31 d-block

    float4 kl[8];
    F4u vl[8];

    auto stage_load = [&](int kv0) {
        const float* kp = kg + base + (size_t)(kv0 + krow) * HD_ + 4 * kc;
        #pragma unroll
        for (int ii = 0; ii < 8; ++ii) kl[ii] = *(const float4*)(kp + 16 * ii);
        const float* vp = vg + base + (size_t)(kv0 + 8 * va) * HD_ + 4 * vbc;
        #pragma unroll
        for (int i = 0; i < 8; ++i) vl[i].v = *(const float4*)(vp + (size_t)i * HD_);
    };

    auto stage_write = [&]() {
        char* kb = (char*)&Kb[0];
        const int kswz = (krow & 7) << 4;
        #pragma unroll
        for (int ii = 0; ii < 8; ++ii) {
            int dby = 8 * (kc + 4 * ii);
            uint2 w;
            w.x = pk2(kl[ii].x, kl[ii].y);
            w.y = pk2(kl[ii].z, kl[ii].w);
            *(uint2*)(kb + ((krow * 256 + dby) ^ kswz)) = w;
        }
        char* vbuf = (char*)&Vb[0];
        #pragma unroll
        for (int j = 0; j < 4; ++j) {
            int d = 4 * vbc + j;
            uint4 w;
            w.x = pk2(vl[0].x4[j], vl[1].x4[j]);
            w.y = pk2(vl[2].x4[j], vl[3].x4[j]);
            w.z = pk2(vl[4].x4[j], vl[5].x4[j]);
            w.w = pk2(vl[6].x4[j], vl[7].x4[j]);
            *(uint4*)(vbuf + ((d * 128 + 16 * va) ^ ((d & 7) << 4))) = w;
        }
    };

    // ---- prologue
    stage_load(0);

    // Q fragments (B-operand: q=lane&31, d = 16*kt + 8*h2 + e), scale*log2(e)
    const float qscale = 0.08838834764831845f * 1.4426950408889634f;
    bf16x8 qf[8];
    {
        const float* qp = qg + base + (size_t)(q0 + wv * 32 + rl) * HD_;
        #pragma unroll
        for (int kt = 0; kt < 8; ++kt) {
            int d0 = kt * 16 + h2 * 8;
            float4 x = *(const float4*)(qp + d0);
            float4 y = *(const float4*)(qp + d0 + 4);
            BF8u t;
            t.u[0] = pk2(x.x * qscale, x.y * qscale);
            t.u[1] = pk2(x.z * qscale, x.w * qscale);
            t.u[2] = pk2(y.x * qscale, y.y * qscale);
            t.u[3] = pk2(y.z * qscale, y.w * qscale);
            qf[kt] = t.v;
        }
    }

    stage_write();
    __syncthreads();

    f32x16 o0 = (f32x16)0.0f, o1 = (f32x16)0.0f, o2 = (f32x16)0.0f, o3 = (f32x16)0.0f;
    float m = -__builtin_inff(), lsum = 0.0f;

    const int cswz = (rl & 7) << 4;
    const char* kb = (const char*)&Kb[0];
    const char* vb = (const char*)&Vb[0];

    for (int t = 0; t < NTILE; ++t) {
        // issue next tile's global loads first: hide HBM/L2 latency under compute
        if (t + 1 < NTILE) stage_load((t + 1) * KVB);

        // ---- QK^T (swapped): S^T[kv][q] = K · Q^T
        f32x16 s0 = (f32x16)0.0f, s1 = (f32x16)0.0f;
        __builtin_amdgcn_s_setprio(1);
        #pragma unroll
        for (int kt = 0; kt < 8; ++kt) {
            int cb = kt * 32 + h2 * 16;
            bf16x8 a0 = *(const bf16x8*)(kb + ((rl * 256 + cb) ^ cswz));
            bf16x8 a1 = *(const bf16x8*)(kb + (((rl + 32) * 256 + cb) ^ cswz));
            s0 = __builtin_amdgcn_mfma_f32_32x32x16_bf16(a0, qf[kt], s0, 0, 0, 0);
            s1 = __builtin_amdgcn_mfma_f32_32x32x16_bf16(a1, qf[kt], s1, 0, 0, 0);
        }
        __builtin_amdgcn_s_setprio(0);

        // ---- online softmax (log2 domain); lane's q-row = lane&31
        float r8[8];
        #pragma unroll
        for (int i = 0; i < 8; ++i)
            r8[i] = fmaxf(fmaxf(s0[i], s0[i + 8]), fmaxf(s1[i], s1[i + 8]));
        float r4a = fmaxf(r8[0], r8[4]), r4b = fmaxf(r8[1], r8[5]);
        float r4c = fmaxf(r8[2], r8[6]), r4d = fmaxf(r8[3], r8[7]);
        float pmax = fmaxf(fmaxf(r4a, r4b), fmaxf(r4c, r4d));
        pmax = fmaxf(pmax, __shfl_xor(pmax, 32));

        if (__any(pmax > m + 8.0f)) {       // defer-max (T13)
            float mn = fmaxf(m, pmax);
            float al = __builtin_amdgcn_exp2f(m - mn);
            m = mn;
            lsum *= al;
            #pragma unroll
            for (int r = 0; r < 16; ++r) {
                float ar = __shfl(al, (r & 3) + 8 * (r >> 2) + 4 * h2);
                o0[r] *= ar; o1[r] *= ar; o2[r] *= ar; o3[r] *= ar;
            }
        }

        float ps = 0.0f;
        #pragma unroll
        for (int r = 0; r < 16; ++r) { float e = __builtin_amdgcn_exp2f(s0[r] - m); s0[r] = e; ps += e; }
        #pragma unroll
        for (int r = 0; r < 16; ++r) { float e = __builtin_amdgcn_exp2f(s1[r] - m); s1[r] = e; ps += e; }
        lsum += ps;

        // ---- pack P into PV A-fragments: pa[ks]: q=lane&31, kv = 16*ks + 8*h2 + e
        // select-before-shuffle: each lane sends exactly the word its partner needs
        unsigned c0w[2][4], c1w[2][4];
        #pragma unroll
        for (int u = 0; u < 4; ++u) {
            c0w[0][u] = pk2(s0[4 * u], s0[4 * u + 1]);
            c1w[0][u] = pk2(s0[4 * u + 2], s0[4 * u + 3]);
            c0w[1][u] = pk2(s1[4 * u], s1[4 * u + 1]);
            c1w[1][u] = pk2(s1[4 * u + 2], s1[4 * u + 3]);
        }
        bf16x8 pa[4];
        #pragma unroll
        for (int ks = 0; ks < 4; ++ks) {
            const int t2 = ks >> 1, ue = (ks & 1) * 2, uo = ue + 1;
            unsigned sel0 = h2 ? c0w[t2][ue] : c0w[t2][uo];
            unsigned sel1 = h2 ? c1w[t2][ue] : c1w[t2][uo];
            unsigned got0 = (unsigned)__shfl_xor((int)sel0, 32);
            unsigned got1 = (unsigned)__shfl_xor((int)sel1, 32);
            BF8u pt;
            pt.u[0] = h2 ? got0 : c0w[t2][ue];
            pt.u[1] = h2 ? got1 : c1w[t2][ue];
            pt.u[2] = h2 ? c0w[t2][uo] : got0;
            pt.u[3] = h2 ? c1w[t2][uo] : got1;
            pa[ks] = pt.v;
        }

        // ---- PV: O[q][d] += P·V from V^T rows d = 32*mt + rl
        __builtin_amdgcn_s_setprio(1);
        #pragma unroll
        for (int ks = 0; ks < 4; ++ks) {
            int cb = ks * 32 + h2 * 16;
            bf16x8 v0 = *(const bf16x8*)(vb + ((rl * 128 + cb) ^ cswz));
            bf16x8 v1 = *(const bf16x8*)(vb + (((rl + 32) * 128 + cb) ^ cswz));
            bf16x8 v2 = *(const bf16x8*)(vb + (((rl + 64) * 128 + cb) ^ cswz));
            bf16x8 v3 = *(const bf16x8*)(vb + (((rl + 96) * 128 + cb) ^ cswz));
            o0 = __builtin_amdgcn_mfma_f32_32x32x16_bf16(pa[ks], v0, o0, 0, 0, 0);
            o1 = __builtin_amdgcn_mfma_f32_32x32x16_bf16(pa[ks], v1, o1, 0, 0, 0);
            o2 = __builtin_amdgcn_mfma_f32_32x32x16_bf16(pa[ks], v2, o2, 0, 0, 0);
            o3 = __builtin_amdgcn_mfma_f32_32x32x16_bf16(pa[ks], v3, o3, 0, 0, 0);
        }
        __builtin_amdgcn_s_setprio(0);

        if (t + 1 < NTILE) {
            __syncthreads();      // all reads of tile t done; vmcnt drain = natural wait point
            stage_write();
            __syncthreads();      // writes visible before next tile's reads
        }
    }

    // ---- epilogue: LSE + normalized O
    float lt = lsum + __shfl_xor(lsum, 32);
    float inv = 1.0f / lt;
    float lsev = (m + __builtin_amdgcn_logf(lt)) * 0.6931471805599453f;  // v_log_f32 = log2
    if (lane < 32) {
        lseg[(size_t)(b * H_ + h) * S_ + q0 + wv * 32 + rl] = lsev;
    }
    float ir[16];
    #pragma unroll
    for (int r = 0; r < 16; ++r) ir[r] = __shfl(inv, (r & 3) + 8 * (r >> 2) + 4 * h2);

    float* op = outg + base + (size_t)(q0 + wv * 32) * HD_ + rl;
    #pragma unroll
    for (int r = 0; r < 16; ++r) {
        int row = (r & 3) + 8 * (r >> 2) + 4 * h2;
        float* orow = op + (size_t)row * HD_;
        orow[0]  = o0[r] * ir[r];
        orow[32] = o1[r] * ir[r];
        orow[64] = o2[r] * ir[r];
        orow[96] = o3[r] * ir[r];
    }
}

extern "C" void kernel_launch(void* const* d_in, const int* in_sizes, int n_in,
                              void* d_out, int out_size, void* d_ws, size_t ws_size,
                              hipStream_t stream)
{
    const float* q = (const float*)d_in[0];
    const float* k = (const float*)d_in[1];
    const float* v = (const float*)d_in[2];
    float* out = (float*)d_out;
    float* lse = out + (size_t)B_ * S_ * H_ * D_;
    attn_fwd_kernel<<<dim3(B_ * H_ * (S_ / BQ)), dim3(256), 0, stream>>>(q, k, v, out, lse);
}

// Round 4
// 125.781 us; speedup vs baseline: 6.3795x; 6.3795x over previous
//
#include <hip/hip_runtime.h>
#include <hip/hip_bf16.h>

#define B_ 2
#define S_ 2048
#define H_ 16
#define D_ 128
#define HD_ (H_ * D_)
#define KVB 64
#define NTILE (S_ / KVB)
#define BQ 128

typedef short bf16x8 __attribute__((ext_vector_type(8)));
typedef float f32x16 __attribute__((ext_vector_type(16)));

union BF8u { unsigned u[4]; bf16x8 v; };
union F4u { float4 v; float x4[4]; };

__device__ __forceinline__ unsigned pk2(float lo, float hi) {
    __hip_bfloat162 h = __float22bfloat162_rn(make_float2(lo, hi));
    union { __hip_bfloat162 h; unsigned u; } c; c.h = h;
    return c.u;
}

// (256,2): let the allocator keep ~128 VGPRs; (256,4) forced spill-to-scratch
// (R3: 2.4 GB scratch traffic, 5.5x slower). 4 blocks/CU comes from LDS=33KB
// + VGPR<=128 naturally.
__global__ __launch_bounds__(256, 2)
void attn_fwd_kernel(const float* __restrict__ qg,
                     const float* __restrict__ kg,
                     const float* __restrict__ vg,
                     float* __restrict__ outg,
                     float* __restrict__ lseg)
{
    __shared__ unsigned short Kb[KVB * D_];   // [kv][d] bf16, swizzled
    __shared__ unsigned short Vb[D_ * KVB];   // [d][kv] bf16 (V^T), swizzled
    __shared__ float albuf[4][32];            // per-wave broadcast slab (free reads)

    const int tid = threadIdx.x;
    const int lane = tid & 63;
    const int wv = tid >> 6;
    const int rl = lane & 31;
    const int h2 = lane >> 5;

    // XCD-aware swizzle (512 = 8*64, bijective)
    const int bid = blockIdx.x;
    const int L = (bid & 7) * 64 + (bid >> 3);
    const int bh = L >> 4;
    const int qt = L & 15;
    const int b = bh >> 4, h = bh & 15;
    const int q0 = qt * BQ;

    const size_t base = (size_t)b * S_ * HD_ + (size_t)h * D_;

    // ---- staging thread maps (phase-conflict-free)
    const int krow = tid >> 2;                    // 0..63
    const int kc = tid & 3;
    const int va = (tid & 3) | ((tid >> 7) << 2); // 0..7 kv-slot
    const int vbc = (tid >> 2) & 31;              // 0..31 d-block

    float4 kl[8];
    F4u vl[8];

    auto stage_load = [&](int kv0) {
        const float* kp = kg + base + (size_t)(kv0 + krow) * HD_ + 4 * kc;
        #pragma unroll
        for (int ii = 0; ii < 8; ++ii) kl[ii] = *(const float4*)(kp + 16 * ii);
        const float* vp = vg + base + (size_t)(kv0 + 8 * va) * HD_ + 4 * vbc;
        #pragma unroll
        for (int i = 0; i < 8; ++i) vl[i].v = *(const float4*)(vp + (size_t)i * HD_);
    };

    auto stage_write = [&]() {
        char* kb = (char*)&Kb[0];
        const int kswz = (krow & 7) << 4;
        #pragma unroll
        for (int ii = 0; ii < 8; ++ii) {
            int dby = 8 * (kc + 4 * ii);
            uint2 w;
            w.x = pk2(kl[ii].x, kl[ii].y);
            w.y = pk2(kl[ii].z, kl[ii].w);
            *(uint2*)(kb + ((krow * 256 + dby) ^ kswz)) = w;
        }
        char* vbuf = (char*)&Vb[0];
        #pragma unroll
        for (int j = 0; j < 4; ++j) {
            int d = 4 * vbc + j;
            uint4 w;
            w.x = pk2(vl[0].x4[j], vl[1].x4[j]);
            w.y = pk2(vl[2].x4[j], vl[3].x4[j]);
            w.z = pk2(vl[4].x4[j], vl[5].x4[j]);
            w.w = pk2(vl[6].x4[j], vl[7].x4[j]);
            *(uint4*)(vbuf + ((d * 128 + 16 * va) ^ ((d & 7) << 4))) = w;
        }
    };

    // ---- prologue
    stage_load(0);

    // Q fragments (B-operand: q=lane&31, d = 16*kt + 8*h2 + e), scale*log2(e)
    const float qscale = 0.08838834764831845f * 1.4426950408889634f;
    bf16x8 qf[8];
    {
        const float* qp = qg + base + (size_t)(q0 + wv * 32 + rl) * HD_;
        #pragma unroll
        for (int kt = 0; kt < 8; ++kt) {
            int d0 = kt * 16 + h2 * 8;
            float4 x = *(const float4*)(qp + d0);
            float4 y = *(const float4*)(qp + d0 + 4);
            BF8u t;
            t.u[0] = pk2(x.x * qscale, x.y * qscale);
            t.u[1] = pk2(x.z * qscale, x.w * qscale);
            t.u[2] = pk2(y.x * qscale, y.y * qscale);
            t.u[3] = pk2(y.z * qscale, y.w * qscale);
            qf[kt] = t.v;
        }
    }

    stage_write();
    __syncthreads();

    f32x16 o0 = (f32x16)0.0f, o1 = (f32x16)0.0f, o2 = (f32x16)0.0f, o3 = (f32x16)0.0f;
    float m = -__builtin_inff(), lsum = 0.0f;

    const int cswz = (rl & 7) << 4;
    const char* kb = (const char*)&Kb[0];
    const char* vb = (const char*)&Vb[0];

    for (int t = 0; t < NTILE; ++t) {
        // issue next tile's global loads first: hide HBM/L2 latency under compute
        if (t + 1 < NTILE) stage_load((t + 1) * KVB);

        // ---- QK^T (swapped): S^T[kv][q] = K · Q^T
        f32x16 s0 = (f32x16)0.0f, s1 = (f32x16)0.0f;
        __builtin_amdgcn_s_setprio(1);
        #pragma unroll
        for (int kt = 0; kt < 8; ++kt) {
            int cb = kt * 32 + h2 * 16;
            bf16x8 a0 = *(const bf16x8*)(kb + ((rl * 256 + cb) ^ cswz));
            bf16x8 a1 = *(const bf16x8*)(kb + (((rl + 32) * 256 + cb) ^ cswz));
            s0 = __builtin_amdgcn_mfma_f32_32x32x16_bf16(a0, qf[kt], s0, 0, 0, 0);
            s1 = __builtin_amdgcn_mfma_f32_32x32x16_bf16(a1, qf[kt], s1, 0, 0, 0);
        }
        __builtin_amdgcn_s_setprio(0);

        // ---- online softmax (log2 domain); lane's q-row = lane&31
        float r8[8];
        #pragma unroll
        for (int i = 0; i < 8; ++i)
            r8[i] = fmaxf(fmaxf(s0[i], s0[i + 8]), fmaxf(s1[i], s1[i + 8]));
        float r4a = fmaxf(r8[0], r8[4]), r4b = fmaxf(r8[1], r8[5]);
        float r4c = fmaxf(r8[2], r8[6]), r4d = fmaxf(r8[3], r8[7]);
        float pmax = fmaxf(fmaxf(r4a, r4b), fmaxf(r4c, r4d));
        pmax = fmaxf(pmax, __shfl_xor(pmax, 32));

        if (__any(pmax > m + 8.0f)) {       // defer-max (T13)
            float mn = fmaxf(m, pmax);
            float al = __builtin_amdgcn_exp2f(m - mn);
            m = mn;
            lsum *= al;
            // broadcast al per q-row via LDS uniform-address read (free),
            // NOT __shfl broadcast (32-way bpermute conflict — was 1e7 cycles)
            if (h2 == 0) albuf[wv][rl] = al;
            #pragma unroll
            for (int r = 0; r < 16; ++r) {
                float ar = albuf[wv][(r & 3) + 8 * (r >> 2) + 4 * h2];
                o0[r] *= ar; o1[r] *= ar; o2[r] *= ar; o3[r] *= ar;
            }
        }

        float ps = 0.0f;
        #pragma unroll
        for (int r = 0; r < 16; ++r) { float e = __builtin_amdgcn_exp2f(s0[r] - m); s0[r] = e; ps += e; }
        #pragma unroll
        for (int r = 0; r < 16; ++r) { float e = __builtin_amdgcn_exp2f(s1[r] - m); s1[r] = e; ps += e; }
        lsum += ps;

        // ---- pack P into PV A-fragments: pa[ks]: q=lane&31, kv = 16*ks + 8*h2 + e
        // select-before-shuffle (distinct-source xor-32, no broadcast conflict)
        unsigned c0w[2][4], c1w[2][4];
        #pragma unroll
        for (int u = 0; u < 4; ++u) {
            c0w[0][u] = pk2(s0[4 * u], s0[4 * u + 1]);
            c1w[0][u] = pk2(s0[4 * u + 2], s0[4 * u + 3]);
            c0w[1][u] = pk2(s1[4 * u], s1[4 * u + 1]);
            c1w[1][u] = pk2(s1[4 * u + 2], s1[4 * u + 3]);
        }
        bf16x8 pa[4];
        #pragma unroll
        for (int ks = 0; ks < 4; ++ks) {
            const int t2 = ks >> 1, ue = (ks & 1) * 2, uo = ue + 1;
            unsigned sel0 = h2 ? c0w[t2][ue] : c0w[t2][uo];
            unsigned sel1 = h2 ? c1w[t2][ue] : c1w[t2][uo];
            unsigned got0 = (unsigned)__shfl_xor((int)sel0, 32);
            unsigned got1 = (unsigned)__shfl_xor((int)sel1, 32);
            BF8u pt;
            pt.u[0] = h2 ? got0 : c0w[t2][ue];
            pt.u[1] = h2 ? got1 : c1w[t2][ue];
            pt.u[2] = h2 ? c0w[t2][uo] : got0;
            pt.u[3] = h2 ? c1w[t2][uo] : got1;
            pa[ks] = pt.v;
        }

        // ---- PV: O[q][d] += P·V from V^T rows d = 32*mt + rl
        __builtin_amdgcn_s_setprio(1);
        #pragma unroll
        for (int ks = 0; ks < 4; ++ks) {
            int cb = ks * 32 + h2 * 16;
            bf16x8 v0 = *(const bf16x8*)(vb + ((rl * 128 + cb) ^ cswz));
            bf16x8 v1 = *(const bf16x8*)(vb + (((rl + 32) * 128 + cb) ^ cswz));
            bf16x8 v2 = *(const bf16x8*)(vb + (((rl + 64) * 128 + cb) ^ cswz));
            bf16x8 v3 = *(const bf16x8*)(vb + (((rl + 96) * 128 + cb) ^ cswz));
            o0 = __builtin_amdgcn_mfma_f32_32x32x16_bf16(pa[ks], v0, o0, 0, 0, 0);
            o1 = __builtin_amdgcn_mfma_f32_32x32x16_bf16(pa[ks], v1, o1, 0, 0, 0);
            o2 = __builtin_amdgcn_mfma_f32_32x32x16_bf16(pa[ks], v2, o2, 0, 0, 0);
            o3 = __builtin_amdgcn_mfma_f32_32x32x16_bf16(pa[ks], v3, o3, 0, 0, 0);
        }
        __builtin_amdgcn_s_setprio(0);

        if (t + 1 < NTILE) {
            __syncthreads();      // reads of tile t done; vmcnt(0) drain = staged loads ready
            stage_write();
            __syncthreads();      // writes visible before next tile's reads
        }
    }

    // ---- epilogue: LSE + normalized O (inv broadcast via LDS, not shfl)
    float lt = lsum + __shfl_xor(lsum, 32);
    float inv = 1.0f / lt;
    float lsev = (m + __builtin_amdgcn_logf(lt)) * 0.6931471805599453f;  // v_log_f32 = log2
    if (lane < 32) {
        lseg[(size_t)(b * H_ + h) * S_ + q0 + wv * 32 + rl] = lsev;
    }
    __syncthreads();
    if (h2 == 0) albuf[wv][rl] = inv;
    float ir[16];
    #pragma unroll
    for (int r = 0; r < 16; ++r) ir[r] = albuf[wv][(r & 3) + 8 * (r >> 2) + 4 * h2];

    float* op = outg + base + (size_t)(q0 + wv * 32) * HD_ + rl;
    #pragma unroll
    for (int r = 0; r < 16; ++r) {
        int row = (r & 3) + 8 * (r >> 2) + 4 * h2;
        float* orow = op + (size_t)row * HD_;
        orow[0]  = o0[r] * ir[r];
        orow[32] = o1[r] * ir[r];
        orow[64] = o2[r] * ir[r];
        orow[96] = o3[r] * ir[r];
    }
}

extern "C" void kernel_launch(void* const* d_in, const int* in_sizes, int n_in,
                              void* d_out, int out_size, void* d_ws, size_t ws_size,
                              hipStream_t stream)
{
    const float* q = (const float*)d_in[0];
    const float* k = (const float*)d_in[1];
    const float* v = (const float*)d_in[2];
    float* out = (float*)d_out;
    float* lse = out + (size_t)B_ * S_ * H_ * D_;
    attn_fwd_kernel<<<dim3(B_ * H_ * (S_ / BQ)), dim3(256), 0, stream>>>(q, k, v, out, lse);
}